// Round 19
// baseline (358.672 us; speedup 1.0000x reference)
//
#include <hip/hip_runtime.h>
#include <cfloat>

static __device__ __forceinline__ float lrelu(float v) { return v >= 0.f ? v : 0.2f * v; }

typedef __attribute__((ext_vector_type(8))) short bf16x8;
typedef __attribute__((ext_vector_type(8))) unsigned short ushort8;
typedef __attribute__((ext_vector_type(4))) float f32x4;

__device__ __forceinline__ unsigned short f2bf(float x) {
    unsigned u = __float_as_uint(x);
    u += 0x7FFF + ((u >> 16) & 1);          // RNE to bf16
    return (unsigned short)(u >> 16);
}
__device__ __forceinline__ float bf2f(unsigned short h) {
    return __uint_as_float(((unsigned)h) << 16);
}

// monotonic float->uint order map (ascending), exactly invertible
__device__ __forceinline__ unsigned ordmap(float f) {
    unsigned u = __float_as_uint(f);
    return (u & 0x80000000u) ? ~u : (u | 0x80000000u);
}
__device__ __forceinline__ float ordinv(unsigned o) {
    unsigned u = (o & 0x80000000u) ? (o & 0x7FFFFFFFu) : ~o;
    return __uint_as_float(u);
}

// ---------------- batched fp32 -> bf16 hi/lo split (+ fused pw-norm block) ----------------
struct SegT { const float* s; unsigned short* dh; unsigned short* dl; int rows, cols, tr; };
struct Segs { SegT seg[7]; int cum[8]; };

__global__ __launch_bounds__(256) void split_k(Segs S, int total,
                                               const float* __restrict__ pw0,
                                               const float* __restrict__ pw1,
                                               const float* __restrict__ pw2,
                                               float* __restrict__ rn)
{
    if (blockIdx.x == gridDim.x - 1) {
        if (threadIdx.x < 192) {
            int l = threadIdx.x >> 6, lane = threadIdx.x & 63;
            const float* pw = (l == 0) ? pw0 : ((l == 1) ? pw1 : pw2);
            float v0 = pw[lane], v1 = pw[lane + 64];
            float p = v0 * v0 + v1 * v1;
#pragma unroll
            for (int o = 32; o > 0; o >>= 1) p += __shfl_down(p, o);
            if (lane == 0) rn[l] = 1.f / sqrtf(p);
        }
        return;
    }
    int idx = blockIdx.x * 256 + threadIdx.x;
    if (idx >= total) return;
    int si = 0;
    while (idx >= S.cum[si + 1]) si++;
    int o = idx - S.cum[si];
    SegT g = S.seg[si];
    float v = g.s[o];
    unsigned short h = f2bf(v);
    unsigned short l = f2bf(v - bf2f(h));
    int di = o;
    if (g.tr) { int r = o / g.cols, c = o - r * g.cols; di = c * g.rows + r; }
    g.dh[di] = h;
    g.dl[di] = l;
}

// ---------------- MFMA GEMM, BM=128, BN=128, BK=64, 4 waves (each 64x64) ----------------
// Pre-split bf16 hi/lo (3-term Ootomo); reg-staged + software prefetch.
// A rows clamped to M-1 (garbage rows only touch guarded-out outputs).
__global__ __launch_bounds__(256) void gemm_bf2_k(const unsigned short* __restrict__ AH,
                                                  const unsigned short* __restrict__ AL,
                                                  const unsigned short* __restrict__ BTH,
                                                  const unsigned short* __restrict__ BTL,
                                                  const float* __restrict__ bias,
                                                  float* __restrict__ C,
                                                  int M, int K, int N, int relu,
                                                  const float* __restrict__ pwv,
                                                  const float* __restrict__ rnormp,
                                                  float* __restrict__ scv,
                                                  const float* __restrict__ asv,
                                                  const float* __restrict__ adv,
                                                  float* __restrict__ esv,
                                                  float* __restrict__ edv)
{
    __shared__ unsigned short sAH[128 * 64], sAL[128 * 64];   // [row][k], chunk-swizzled
    __shared__ unsigned short sBH[128 * 64], sBL[128 * 64];   // [col][k], chunk-swizzled
    __shared__ float sred[4][128];
    const int tid  = threadIdx.x;
    const int lane = tid & 63;
    const int wave = tid >> 6;
    const int wr = (wave >> 1) * 64;
    const int wc = (wave & 1) * 64;
    const int row0 = blockIdx.x * 128, col0 = blockIdx.y * 128;

    f32x4 acc[4][4];
#pragma unroll
    for (int i = 0; i < 4; i++)
#pragma unroll
        for (int j = 0; j < 4; j++) acc[i][j] = (f32x4){0.f, 0.f, 0.f, 0.f};

    // staging: 128 rows/cols, thread -> row=tid>>1, 4 chunks at (tid&1)*4
    const int a_r  = tid >> 1;
    const int a_cp = (tid & 1) * 4;
    const int a_rg = min(row0 + a_r, M - 1);            // clamp (guards epilogue anyway)
    const unsigned short* ApH = AH + (size_t)a_rg * K + a_cp * 8;
    const unsigned short* ApL = AL + (size_t)a_rg * K + a_cp * 8;
    const int a_sw = a_r & 7;
    int a_s[4];
#pragma unroll
    for (int i = 0; i < 4; i++) a_s[i] = a_r * 64 + (((a_cp + i) ^ a_sw) << 3);

    const int b_c  = tid >> 1;
    const int b_cp = (tid & 1) * 4;
    const unsigned short* BpH = BTH + (size_t)(col0 + b_c) * K + b_cp * 8;
    const unsigned short* BpL = BTL + (size_t)(col0 + b_c) * K + b_cp * 8;
    const int b_sw = b_c & 7;
    int b_s[4];
#pragma unroll
    for (int i = 0; i < 4; i++) b_s[i] = b_c * 64 + (((b_cp + i) ^ b_sw) << 3);

    const int l15 = lane & 15;
    const int kc  = lane >> 4;

    // prologue: load tile 0
    ushort8 vah[4], val[4], vbh[4], vbl[4];
#pragma unroll
    for (int i = 0; i < 4; i++) {
        vah[i] = *reinterpret_cast<const ushort8*>(ApH + i * 8);
        val[i] = *reinterpret_cast<const ushort8*>(ApL + i * 8);
        vbh[i] = *reinterpret_cast<const ushort8*>(BpH + i * 8);
        vbl[i] = *reinterpret_cast<const ushort8*>(BpL + i * 8);
    }

    for (int k0 = 0; k0 < K; k0 += 64) {
        __syncthreads();
#pragma unroll
        for (int i = 0; i < 4; i++) {
            *reinterpret_cast<ushort8*>(&sAH[a_s[i]]) = vah[i];
            *reinterpret_cast<ushort8*>(&sAL[a_s[i]]) = val[i];
            *reinterpret_cast<ushort8*>(&sBH[b_s[i]]) = vbh[i];
            *reinterpret_cast<ushort8*>(&sBL[b_s[i]]) = vbl[i];
        }
        __syncthreads();

        if (k0 + 64 < K) {
            int kn = k0 + 64;
#pragma unroll
            for (int i = 0; i < 4; i++) {
                vah[i] = *reinterpret_cast<const ushort8*>(ApH + kn + i * 8);
                val[i] = *reinterpret_cast<const ushort8*>(ApL + kn + i * 8);
                vbh[i] = *reinterpret_cast<const ushort8*>(BpH + kn + i * 8);
                vbl[i] = *reinterpret_cast<const ushort8*>(BpL + kn + i * 8);
            }
        }

#pragma unroll
        for (int ks = 0; ks < 2; ks++) {
            const int ch = ks * 4 + kc;
            bf16x8 aH[4], aL[4], bH[4], bL[4];
#pragma unroll
            for (int fi = 0; fi < 4; fi++) {
                int r = wr + fi * 16 + l15;
                int sidx = r * 64 + ((ch ^ (r & 7)) << 3);
                aH[fi] = *reinterpret_cast<const bf16x8*>(&sAH[sidx]);
                aL[fi] = *reinterpret_cast<const bf16x8*>(&sAL[sidx]);
            }
#pragma unroll
            for (int fj = 0; fj < 4; fj++) {
                int c = wc + fj * 16 + l15;
                int sidx = c * 64 + ((ch ^ (c & 7)) << 3);
                bH[fj] = *reinterpret_cast<const bf16x8*>(&sBH[sidx]);
                bL[fj] = *reinterpret_cast<const bf16x8*>(&sBL[sidx]);
            }
#pragma unroll
            for (int fi = 0; fi < 4; fi++)
#pragma unroll
                for (int fj = 0; fj < 4; fj++) {
                    acc[fi][fj] = __builtin_amdgcn_mfma_f32_16x16x32_bf16(aH[fi], bH[fj], acc[fi][fj], 0, 0, 0);
                    acc[fi][fj] = __builtin_amdgcn_mfma_f32_16x16x32_bf16(aH[fi], bL[fj], acc[fi][fj], 0, 0, 0);
                    acc[fi][fj] = __builtin_amdgcn_mfma_f32_16x16x32_bf16(aL[fi], bH[fj], acc[fi][fj], 0, 0, 0);
                }
        }
    }

    float pwl[4], asl[4], adl[4];
    if (scv) {
#pragma unroll
        for (int fj = 0; fj < 4; fj++) pwl[fj] = pwv[wc + fj * 16 + l15];
    }
    const int hd = blockIdx.y;
    if (esv) {
#pragma unroll
        for (int fj = 0; fj < 4; fj++) {
            int cl = wc + fj * 16 + l15;
            asl[fj] = asv[hd * 128 + cl];
            adl[fj] = adv[hd * 128 + cl];
        }
    }
    float pd[4][4]  = {{0.f,0.f,0.f,0.f},{0.f,0.f,0.f,0.f},{0.f,0.f,0.f,0.f},{0.f,0.f,0.f,0.f}};
    float pds[4][4] = {{0.f,0.f,0.f,0.f},{0.f,0.f,0.f,0.f},{0.f,0.f,0.f,0.f},{0.f,0.f,0.f,0.f}};
    float pdd[4][4] = {{0.f,0.f,0.f,0.f},{0.f,0.f,0.f,0.f},{0.f,0.f,0.f,0.f},{0.f,0.f,0.f,0.f}};
#pragma unroll
    for (int fi = 0; fi < 4; fi++) {
        int rbase = row0 + wr + fi * 16 + (lane >> 4) * 4;
#pragma unroll
        for (int q = 0; q < 4; q++) {
            int r = rbase + q;
            if (r < M) {
#pragma unroll
                for (int fj = 0; fj < 4; fj++) {
                    int c = col0 + wc + fj * 16 + l15;
                    float v = acc[fi][fj][q];
                    if (bias) v += bias[c];
                    if (relu) v = fmaxf(v, 0.f);
                    C[(size_t)r * N + c] = v;
                    if (scv) pd[fi][q] += v * pwl[fj];
                    if (esv) { pds[fi][q] += v * asl[fj]; pdd[fi][q] += v * adl[fj]; }
                }
            }
        }
    }
    if (scv) {
        float rn0 = rnormp[0];
#pragma unroll
        for (int fi = 0; fi < 4; fi++)
#pragma unroll
            for (int q = 0; q < 4; q++) {
                float s = pd[fi][q];
                s += __shfl_xor(s, 1);
                s += __shfl_xor(s, 2);
                s += __shfl_xor(s, 4);
                s += __shfl_xor(s, 8);
                if (l15 == 0) sred[wc >> 6][wr + fi * 16 + (lane >> 4) * 4 + q] = s;
            }
        __syncthreads();
        if (tid < 128 && row0 + tid < M)
            scv[row0 + tid] = tanhf((sred[0][tid] + sred[1][tid]) * rn0);
    }
    if (esv) {
#pragma unroll
        for (int fi = 0; fi < 4; fi++)
#pragma unroll
            for (int q = 0; q < 4; q++) {
                float s = pds[fi][q];
                s += __shfl_xor(s, 1);
                s += __shfl_xor(s, 2);
                s += __shfl_xor(s, 4);
                s += __shfl_xor(s, 8);
                float d = pdd[fi][q];
                d += __shfl_xor(d, 1);
                d += __shfl_xor(d, 2);
                d += __shfl_xor(d, 4);
                d += __shfl_xor(d, 8);
                if (l15 == 0) {
                    int rl = wr + fi * 16 + (lane >> 4) * 4 + q;
                    sred[wc >> 6][rl] = s;
                    sred[2 + (wc >> 6)][rl] = d;
                }
            }
        __syncthreads();
        if (tid < 128 && row0 + tid < M) {
            int r = row0 + tid;
            esv[(size_t)r * 3 + hd] = sred[0][tid] + sred[1][tid];
            edv[(size_t)r * 3 + hd] = sred[2][tid] + sred[3][tid];
        }
    }
}

// ---------------- small-M GEMM (MLP head, M=64): one thread per output ----------------
__global__ __launch_bounds__(256) void gemm_small_k(const float* __restrict__ A,
                                                    const float* __restrict__ B,
                                                    const float* __restrict__ bias,
                                                    float* __restrict__ C,
                                                    int M, int K, int N, int relu)
{
    int idx = blockIdx.x * 256 + threadIdx.x;
    if (idx >= M * N) return;
    int r = idx / N, c = idx - r * N;
    const float* ap = A + (size_t)r * K;
    const float* bp = B + c;
    float s = 0.f;
#pragma unroll 8
    for (int k = 0; k < K; k++) s += ap[k] * bp[(size_t)k * N];
    if (bias) s += bias[c];
    if (relu) s = fmaxf(s, 0.f);
    C[idx] = s;
}

// ---------------- per-graph CSR build + softmax max/den (one 512-thr block per graph) ----------------
__global__ __launch_bounds__(512) void csr_k(const int* __restrict__ src,
                                             const int* __restrict__ dst,
                                             const int* __restrict__ valid,
                                             const float* __restrict__ es,
                                             const float* __restrict__ ed,
                                             int* __restrict__ csr,
                                             int* __restrict__ beg,
                                             int* __restrict__ end,
                                             float* __restrict__ wmx,
                                             float* __restrict__ winv,
                                             float* __restrict__ wself,
                                             int per)
{
    __shared__ int sdeg[512];
    __shared__ int soff[512];
    __shared__ float ses[1536];
    __shared__ float sed[1536];
    const int g = blockIdx.x;
    const int t = threadIdx.x;
    const int bn = g * per;
    const int be = g * 2048;
    sdeg[t] = 0;
    for (int i = t; i < per * 3; i += 512) {
        ses[i] = es[(size_t)bn * 3 + i];
        sed[i] = ed[(size_t)bn * 3 + i];
    }
    __syncthreads();
#pragma unroll
    for (int j = 0; j < 4; j++) {
        int e = be + j * 512 + t;
        if (!valid || valid[e]) atomicAdd(&sdeg[dst[e] - bn], 1);
    }
    __syncthreads();
    soff[t] = sdeg[t];
    __syncthreads();
    for (int d = 1; d < 512; d <<= 1) {
        int v = (t >= d) ? soff[t - d] : 0;
        __syncthreads();
        soff[t] += v;
        __syncthreads();
    }
    const int deg_t = sdeg[t];
    const int excl = soff[t] - deg_t;
    if (t < per) { beg[bn + t] = be + excl; end[bn + t] = be + excl + deg_t; }
    __syncthreads();
    sdeg[t] = excl;
    __syncthreads();
#pragma unroll
    for (int j = 0; j < 4; j++) {
        int e = be + j * 512 + t;
        if (!valid || valid[e]) {
            int p = atomicAdd(&sdeg[dst[e] - bn], 1);
            csr[be + p] = e;
        }
    }
    __syncthreads();
    if (t < per) {
        float edv[3], m[3], den[3], selfl[3];
#pragma unroll
        for (int h = 0; h < 3; h++) {
            edv[h] = sed[t * 3 + h];
            selfl[h] = lrelu(ses[t * 3 + h] + edv[h]);
            m[h] = selfl[h];
            den[h] = 1.f;
        }
        const int pb = excl, pe = excl + deg_t;
        for (int p = pb; p < pe; p++) {
            int e = csr[be + p];
            int sl = src[e] - bn;
#pragma unroll
            for (int h = 0; h < 3; h++) {
                float l = lrelu(ses[sl * 3 + h] + edv[h]);
                if (l <= m[h]) den[h] += __expf(l - m[h]);
                else { den[h] = den[h] * __expf(m[h] - l) + 1.f; m[h] = l; }
            }
        }
#pragma unroll
        for (int h = 0; h < 3; h++) {
            float inv = 1.f / (den[h] + 1e-16f);
            wmx[(size_t)(bn + t) * 3 + h] = m[h];
            winv[(size_t)(bn + t) * 3 + h] = inv;
            wself[(size_t)(bn + t) * 3 + h] = __expf(selfl[h] - m[h]) * inv;
        }
    }
}

// ---------------- alpha+gather fused: one wave per dst, lane-parallel weight precompute ----------------
__global__ __launch_bounds__(256) void agg2_k(const float* __restrict__ H,
                                              const float* __restrict__ es,
                                              const float* __restrict__ ed,
                                              const float* __restrict__ wmx,
                                              const float* __restrict__ winv,
                                              const float* __restrict__ wself,
                                              const int* __restrict__ beg,
                                              const int* __restrict__ end,
                                              const int* __restrict__ csr,
                                              const int* __restrict__ srcArr,
                                              const float* __restrict__ bias,
                                              unsigned short* __restrict__ outH,
                                              unsigned short* __restrict__ outL, int n)
{
    int nwg = gridDim.x;
    int bid = blockIdx.x;
    int swz = (bid & 7) * (nwg >> 3) + (bid >> 3);
    int wid = swz * 4 + (int)(threadIdx.x >> 6);
    int lane = threadIdx.x & 63;
    if (wid >= n) return;
    const int d = wid;
    float edv[3], mxv[3], ivv[3], wsf[3];
#pragma unroll
    for (int h = 0; h < 3; h++) {
        edv[h] = ed[(size_t)d * 3 + h];
        mxv[h] = wmx[(size_t)d * 3 + h];
        ivv[h] = winv[(size_t)d * 3 + h];
        wsf[h] = wself[(size_t)d * 3 + h];
    }
    float acc[6];
    const float* hp = H + (size_t)d * 384;
#pragma unroll
    for (int j = 0; j < 6; j++) acc[j] = wsf[j >> 1] * hp[lane + 64 * j];
    const int pb = beg[d], pe = end[d];
    for (int base = pb; base < pe; base += 64) {
        const int cnt = min(64, pe - base);
        int sl = 0;
        float wl0 = 0.f, wl1 = 0.f, wl2 = 0.f;
        if (lane < cnt) {
            int e = csr[base + lane];
            int s = srcArr[e];
            sl = s;
            wl0 = __expf(lrelu(es[(size_t)s * 3 + 0] + edv[0]) - mxv[0]) * ivv[0];
            wl1 = __expf(lrelu(es[(size_t)s * 3 + 1] + edv[1]) - mxv[1]) * ivv[1];
            wl2 = __expf(lrelu(es[(size_t)s * 3 + 2] + edv[2]) - mxv[2]) * ivv[2];
        }
        for (int j = 0; j < cnt; j++) {
            int s = __shfl(sl, j);
            float w0 = __shfl(wl0, j);
            float w1 = __shfl(wl1, j);
            float w2 = __shfl(wl2, j);
            const float* sp = H + (size_t)s * 384;
            acc[0] += w0 * sp[lane];
            acc[1] += w0 * sp[lane + 64];
            acc[2] += w1 * sp[lane + 128];
            acc[3] += w1 * sp[lane + 192];
            acc[4] += w2 * sp[lane + 256];
            acc[5] += w2 * sp[lane + 320];
        }
    }
#pragma unroll
    for (int j = 0; j < 6; j++) {
        float v = acc[j] + bias[lane + 64 * j];
        unsigned short h = f2bf(v);
        outH[(size_t)d * 384 + lane + 64 * j] = h;
        outL[(size_t)d * 384 + lane + 64 * j] = f2bf(v - bf2f(h));
    }
}

// ---------------- per-graph top-k select + fused edge remap (u64-packed bitonic) ----------------
__global__ __launch_bounds__(512) void select_k(const float* __restrict__ sc,
                                                const int* __restrict__ s_old,
                                                const int* __restrict__ d_old,
                                                const int* __restrict__ v_old,
                                                int per, int k,
                                                int* __restrict__ perm, float* __restrict__ ps,
                                                int* __restrict__ s_new,
                                                int* __restrict__ d_new,
                                                int* __restrict__ v_new)
{
    __shared__ unsigned long long skey[512];
    __shared__ int snew[512];
    const int b = blockIdx.x;
    const int t = threadIdx.x;
    const int bn = b * per;

    if (t < per) {
        unsigned o = ~ordmap(sc[bn + t]);
        skey[t] = ((unsigned long long)o << 32) | (unsigned)t;
    } else {
        skey[t] = 0xFFFFFFFFFFFFFFFFull;
    }
    __syncthreads();
    for (int kk = 2; kk <= 512; kk <<= 1)
        for (int j = kk >> 1; j > 0; j >>= 1) {
            int ixj = t ^ j;
            if (ixj > t) {
                unsigned long long a = skey[t], bq = skey[ixj];
                bool up = ((t & kk) == 0);
                if (up ? (a > bq) : (a < bq)) { skey[t] = bq; skey[ixj] = a; }
            }
            __syncthreads();
        }
    {
        unsigned long long kv = skey[t];
        int idx = (int)(kv & 0xFFFFFFFFull);
        if (idx < per) snew[idx] = (t < k) ? (b * k + t) : -1;
        if (t < k) {
            perm[b * k + t] = bn + idx;
            ps[b * k + t] = ordinv(~(unsigned)(kv >> 32));
        }
    }
    __syncthreads();

    if (s_new) {
        const int be = b * 2048;
#pragma unroll
        for (int j = 0; j < 4; j++) {
            int e = be + j * 512 + t;
            int v = v_old ? v_old[e] : 1;
            int ns = -1, nd = -1;
            if (v) { ns = snew[s_old[e] - bn]; nd = snew[d_old[e] - bn]; }
            int ok = (v && ns >= 0 && nd >= 0) ? 1 : 0;
            s_new[e] = ok ? ns : 0;
            d_new[e] = ok ? nd : 0;
            v_new[e] = ok;
        }
    }
}

// ---------------- gated copy of kept nodes: bf16 hi/lo only (one wave per new node) ----------------
__global__ __launch_bounds__(256) void gate_k(const float* __restrict__ H,
                                              const int* __restrict__ perm,
                                              const float* __restrict__ ps,
                                              unsigned short* __restrict__ XH,
                                              unsigned short* __restrict__ XL, int nNew)
{
    int wid = (int)((blockIdx.x * 256 + threadIdx.x) >> 6);
    int lane = threadIdx.x & 63;
    if (wid >= nNew) return;
    int o = perm[wid];
    float g = ps[wid];
    float v0 = H[(size_t)o * 128 + lane] * g;
    float v1 = H[(size_t)o * 128 + 64 + lane] * g;
    unsigned short h0 = f2bf(v0), h1 = f2bf(v1);
    XH[(size_t)wid * 128 + lane] = h0;
    XH[(size_t)wid * 128 + 64 + lane] = h1;
    XL[(size_t)wid * 128 + lane] = f2bf(v0 - bf2f(h0));
    XL[(size_t)wid * 128 + 64 + lane] = f2bf(v1 - bf2f(h1));
}

// ---------------- combined global max+mean pool over all three layers (bf16 hi/lo inputs) ----------------
__global__ __launch_bounds__(1024) void gpool3_k(const unsigned short* __restrict__ X1H,
                                                 const unsigned short* __restrict__ X1L,
                                                 const unsigned short* __restrict__ X2H,
                                                 const unsigned short* __restrict__ X2L,
                                                 const unsigned short* __restrict__ X3H,
                                                 const unsigned short* __restrict__ X3L,
                                                 int k1, int k2, int k3,
                                                 float* __restrict__ z)
{
    __shared__ float smx[8][128];
    __shared__ float ssm[8][128];
    const int b = blockIdx.x;
    const int col = threadIdx.x & 127;
    const int rg = threadIdx.x >> 7;
    const unsigned short* XsH[3] = {X1H, X2H, X3H};
    const unsigned short* XsL[3] = {X1L, X2L, X3L};
    const int ks[3] = {k1, k2, k3};
    float accm = 0.f, accs = 0.f;
#pragma unroll
    for (int L = 0; L < 3; L++) {
        const int k = ks[L];
        const unsigned short* xh = XsH[L] + (size_t)b * k * 128 + col;
        const unsigned short* xl = XsL[L] + (size_t)b * k * 128 + col;
        float mx = -FLT_MAX, sm = 0.f;
        int r = rg;
#pragma unroll 4
        for (; r + 32 <= k; r += 32) {
            float v0 = bf2f(xh[(size_t)(r + 0)  * 128]) + bf2f(xl[(size_t)(r + 0)  * 128]);
            float v1 = bf2f(xh[(size_t)(r + 8)  * 128]) + bf2f(xl[(size_t)(r + 8)  * 128]);
            float v2 = bf2f(xh[(size_t)(r + 16) * 128]) + bf2f(xl[(size_t)(r + 16) * 128]);
            float v3 = bf2f(xh[(size_t)(r + 24) * 128]) + bf2f(xl[(size_t)(r + 24) * 128]);
            mx = fmaxf(fmaxf(fmaxf(mx, v0), fmaxf(v1, v2)), v3);
            sm += v0 + v1 + v2 + v3;
        }
        for (; r < k; r += 8) {
            float v = bf2f(xh[(size_t)r * 128]) + bf2f(xl[(size_t)r * 128]);
            mx = fmaxf(mx, v);
            sm += v;
        }
        smx[rg][col] = mx;
        ssm[rg][col] = sm;
        __syncthreads();
        if (rg == 0) {
#pragma unroll
            for (int i = 1; i < 8; i++) { mx = fmaxf(mx, smx[i][col]); sm += ssm[i][col]; }
            accm += mx;
            accs += sm / (float)k;
        }
        __syncthreads();
    }
    if (rg == 0) {
        z[b * 256 + col] = accm;
        z[b * 256 + 128 + col] = accs;
    }
}

extern "C" void kernel_launch(void* const* d_in, const int* in_sizes, int n_in,
                              void* d_out, int out_size, void* d_ws, size_t ws_size,
                              hipStream_t stream)
{
    (void)in_sizes; (void)n_in; (void)out_size; (void)ws_size;

    const float* x   = (const float*)d_in[0];
    const int*   ei  = (const int*)d_in[2];
    const float* W1  = (const float*)d_in[4];
    const float* as1 = (const float*)d_in[5];
    const float* ad1 = (const float*)d_in[6];
    const float* b1  = (const float*)d_in[7];
    const float* Wh1 = (const float*)d_in[8];
    const float* bh1 = (const float*)d_in[9];
    const float* pw1 = (const float*)d_in[10];
    const float* W2  = (const float*)d_in[11];
    const float* as2 = (const float*)d_in[12];
    const float* ad2 = (const float*)d_in[13];
    const float* b2  = (const float*)d_in[14];
    const float* Wh2 = (const float*)d_in[15];
    const float* bh2 = (const float*)d_in[16];
    const float* pw2 = (const float*)d_in[17];
    const float* W3  = (const float*)d_in[18];
    const float* as3 = (const float*)d_in[19];
    const float* ad3 = (const float*)d_in[20];
    const float* b3  = (const float*)d_in[21];
    const float* Wh3 = (const float*)d_in[22];
    const float* bh3 = (const float*)d_in[23];
    const float* pw3 = (const float*)d_in[24];
    const float* Wl1 = (const float*)d_in[25];
    const float* bl1 = (const float*)d_in[26];
    const float* Wl2 = (const float*)d_in[27];
    const float* bl2 = (const float*)d_in[28];
    float* out = (float*)d_out;

    const int E = 131072;
    const int n1 = 32768, per1 = 512, k1 = 410;
    const int n2 = 64 * k1, per2 = k1, k2 = 205;   // 26240, 410, 205
    const int n3 = 64 * k2, per3 = k2, k3 = 41;    // 13120, 205, 41
    const int n4 = 64 * k3;                        // 2624

    // ---- workspace carve ----
    char* wsb = (char*)d_ws;
    size_t off = 0;
    auto alloc = [&](size_t bytes) -> void* {
        void* p = wsb + off;
        off += (bytes + 255) & ~(size_t)255;
        return p;
    };
    float* A    = (float*)alloc((size_t)n1 * 384 * 4);
    unsigned short* BfH = (unsigned short*)alloc((size_t)n1 * 384 * 2);
    unsigned short* BfL = (unsigned short*)alloc((size_t)n1 * 384 * 2);
    unsigned short* X0H = (unsigned short*)alloc((size_t)n1 * 128 * 2);
    unsigned short* X0L = (unsigned short*)alloc((size_t)n1 * 128 * 2);
    unsigned short* X1H = (unsigned short*)alloc((size_t)n2 * 128 * 2);
    unsigned short* X1L = (unsigned short*)alloc((size_t)n2 * 128 * 2);
    unsigned short* X2H = (unsigned short*)alloc((size_t)n3 * 128 * 2);
    unsigned short* X2L = (unsigned short*)alloc((size_t)n3 * 128 * 2);
    unsigned short* X3H = (unsigned short*)alloc((size_t)n4 * 128 * 2);
    unsigned short* X3L = (unsigned short*)alloc((size_t)n4 * 128 * 2);
    unsigned short* WT[6], *WTl[6];
    for (int i = 0; i < 6; i++) {
        WT[i]  = (unsigned short*)alloc((size_t)49152 * 2);
        WTl[i] = (unsigned short*)alloc((size_t)49152 * 2);
    }
    float* ES   = (float*)alloc((size_t)n1 * 3 * 4);
    float* ED   = (float*)alloc((size_t)n1 * 3 * 4);
    float* SC   = (float*)alloc((size_t)n1 * 4);
    int*   CSR  = (int*)alloc((size_t)E * 4);
    int*   BEG  = (int*)alloc((size_t)n1 * 4);
    int*   END  = (int*)alloc((size_t)n1 * 4);
    int*   SRCA = (int*)alloc((size_t)E * 4);
    int*   DSTA = (int*)alloc((size_t)E * 4);
    int*   VALA = (int*)alloc((size_t)E * 4);
    int*   SRCB = (int*)alloc((size_t)E * 4);
    int*   DSTB = (int*)alloc((size_t)E * 4);
    int*   VALB = (int*)alloc((size_t)E * 4);
    int*   PERM = (int*)alloc((size_t)n2 * 4);
    float* PSC  = (float*)alloc((size_t)n2 * 4);
    float* WMX  = (float*)alloc((size_t)n1 * 3 * 4);
    float* WINV = (float*)alloc((size_t)n1 * 3 * 4);
    float* WSELF= (float*)alloc((size_t)n1 * 3 * 4);
    float* RN   = (float*)alloc((size_t)4 * 4);
    float* Z    = (float*)alloc((size_t)64 * 256 * 4);
    float* ZH   = (float*)alloc((size_t)64 * 512 * 4);

    // ---- upfront: operand split + 1/||pw|| (fused) ----
    {
        Segs S;
        const float* srcs[7] = {x, W1, Wh1, W2, Wh2, W3, Wh3};
        unsigned short* dh[7] = {X0H, WT[0], WT[1], WT[2], WT[3], WT[4], WT[5]};
        unsigned short* dl[7] = {X0L, WTl[0], WTl[1], WTl[2], WTl[3], WTl[4], WTl[5]};
        int rows[7] = {n1, 128, 384, 128, 384, 128, 384};
        int cols[7] = {128, 384, 128, 384, 128, 384, 128};
        int trs[7]  = {0, 1, 1, 1, 1, 1, 1};
        int cum = 0;
        for (int i = 0; i < 7; i++) {
            S.seg[i] = SegT{srcs[i], dh[i], dl[i], rows[i], cols[i], trs[i]};
            S.cum[i] = cum;
            cum += rows[i] * cols[i];
        }
        S.cum[7] = cum;
        split_k<<<(cum + 255) / 256 + 1, 256, 0, stream>>>(S, cum, pw1, pw2, pw3, RN);
    }

    auto layer = [&](const unsigned short* xh, const unsigned short* xl,
                     int n, int per, int kk, int lidx,
                     const int* src, const int* dst, const int* val,
                     const unsigned short* wt, const unsigned short* wtl,
                     const float* as_, const float* ad_, const float* bb,
                     const unsigned short* wht, const unsigned short* whtl, const float* bh,
                     const float* pw,
                     unsigned short* XnH, unsigned short* XnL,
                     int* srcN, int* dstN, int* valN)
    {
        int nNew = 64 * kk;
        int gm = (n + 127) / 128;
        // GEMM-1 with fused e_src/e_dst epilogue (blockIdx.y == head)
        gemm_bf2_k<<<dim3(gm, 3), 256, 0, stream>>>(xh, xl, wt, wtl, nullptr, A, n, 128, 384, 0,
                                                    nullptr, nullptr, nullptr,
                                                    as_, ad_, ES, ED);
        csr_k<<<64, 512, 0, stream>>>(src, dst, val, ES, ED, CSR, BEG, END, WMX, WINV, WSELF, per);
        agg2_k<<<n / 4, 256, 0, stream>>>(A, ES, ED, WMX, WINV, WSELF, BEG, END, CSR, src, bb, BfH, BfL, n);
        // GEMM-2 with fused score epilogue
        gemm_bf2_k<<<dim3(gm, 1), 256, 0, stream>>>(BfH, BfL, wht, whtl, bh, A, n, 384, 128, 1,
                                                    pw, RN + lidx, SC,
                                                    nullptr, nullptr, nullptr, nullptr);
        select_k<<<64, 512, 0, stream>>>(SC, src, dst, val, per, kk, PERM, PSC, srcN, dstN, valN);
        gate_k<<<nNew / 4, 256, 0, stream>>>(A, PERM, PSC, XnH, XnL, nNew);
    };

    layer(X0H, X0L, n1, per1, k1, 0, ei,   ei + E, nullptr,
          WT[0], WTl[0], as1, ad1, b1, WT[1], WTl[1], bh1, pw1,
          X1H, X1L, SRCA, DSTA, VALA);
    layer(X1H, X1L, n2, per2, k2, 1, SRCA, DSTA, VALA,
          WT[2], WTl[2], as2, ad2, b2, WT[3], WTl[3], bh2, pw2,
          X2H, X2L, SRCB, DSTB, VALB);
    layer(X2H, X2L, n3, per3, k3, 2, SRCB, DSTB, VALB,
          WT[4], WTl[4], as3, ad3, b3, WT[5], WTl[5], bh3, pw3,
          X3H, X3L, nullptr, nullptr, nullptr);

    gpool3_k<<<64, 1024, 0, stream>>>(X1H, X1L, X2H, X2L, X3H, X3L, k1, k2, k3, Z);

    gemm_small_k<<<(64 * 512 + 255) / 256, 256, 0, stream>>>(Z,  Wl1, bl1, ZH,  64, 256, 512, 1);
    gemm_small_k<<<(64 * 256 + 255) / 256, 256, 0, stream>>>(ZH, Wl2, bl2, out, 64, 512, 256, 0);
}

// Round 20
// 313.487 us; speedup vs baseline: 1.1441x; 1.1441x over previous
//
#include <hip/hip_runtime.h>
#include <cfloat>

static __device__ __forceinline__ float lrelu(float v) { return v >= 0.f ? v : 0.2f * v; }

typedef __attribute__((ext_vector_type(8))) short bf16x8;
typedef __attribute__((ext_vector_type(8))) unsigned short ushort8;
typedef __attribute__((ext_vector_type(4))) float f32x4;

__device__ __forceinline__ unsigned short f2bf(float x) {
    unsigned u = __float_as_uint(x);
    u += 0x7FFF + ((u >> 16) & 1);          // RNE to bf16
    return (unsigned short)(u >> 16);
}
__device__ __forceinline__ float bf2f(unsigned short h) {
    return __uint_as_float(((unsigned)h) << 16);
}

// monotonic float->uint order map (ascending), exactly invertible
__device__ __forceinline__ unsigned ordmap(float f) {
    unsigned u = __float_as_uint(f);
    return (u & 0x80000000u) ? ~u : (u | 0x80000000u);
}
__device__ __forceinline__ float ordinv(unsigned o) {
    unsigned u = (o & 0x80000000u) ? (o & 0x7FFFFFFFu) : ~o;
    return __uint_as_float(u);
}

// ---------------- batched fp32 -> bf16 hi/lo split (+ fused pw-norm block) ----------------
struct SegT { const float* s; unsigned short* dh; unsigned short* dl; int rows, cols, tr; };
struct Segs { SegT seg[7]; int cum[8]; };

__global__ __launch_bounds__(256) void split_k(Segs S, int total,
                                               const float* __restrict__ pw0,
                                               const float* __restrict__ pw1,
                                               const float* __restrict__ pw2,
                                               float* __restrict__ rn)
{
    if (blockIdx.x == gridDim.x - 1) {
        if (threadIdx.x < 192) {
            int l = threadIdx.x >> 6, lane = threadIdx.x & 63;
            const float* pw = (l == 0) ? pw0 : ((l == 1) ? pw1 : pw2);
            float v0 = pw[lane], v1 = pw[lane + 64];
            float p = v0 * v0 + v1 * v1;
#pragma unroll
            for (int o = 32; o > 0; o >>= 1) p += __shfl_down(p, o);
            if (lane == 0) rn[l] = 1.f / sqrtf(p);
        }
        return;
    }
    int idx = blockIdx.x * 256 + threadIdx.x;
    if (idx >= total) return;
    int si = 0;
    while (idx >= S.cum[si + 1]) si++;
    int o = idx - S.cum[si];
    SegT g = S.seg[si];
    float v = g.s[o];
    unsigned short h = f2bf(v);
    unsigned short l = f2bf(v - bf2f(h));
    int di = o;
    if (g.tr) { int r = o / g.cols, c = o - r * g.cols; di = c * g.rows + r; }
    g.dh[di] = h;
    g.dl[di] = l;
}

// ---------------- MFMA GEMM on pre-split bf16 hi/lo (3-term Ootomo), BK=64 ----------------
// Reg-staged with software prefetch (round-17/18 proven structure; BM=64 is the
// occupancy-optimal point for the dual-operand hi/lo scheme — BM=128 regressed).
__global__ __launch_bounds__(256) void gemm_bf2_k(const unsigned short* __restrict__ AH,
                                                  const unsigned short* __restrict__ AL,
                                                  const unsigned short* __restrict__ BTH,
                                                  const unsigned short* __restrict__ BTL,
                                                  const float* __restrict__ bias,
                                                  float* __restrict__ C,
                                                  int M, int K, int N, int relu,
                                                  const float* __restrict__ pwv,
                                                  const float* __restrict__ rnormp,
                                                  float* __restrict__ scv,
                                                  const float* __restrict__ asv,
                                                  const float* __restrict__ adv,
                                                  float* __restrict__ esv,
                                                  float* __restrict__ edv)
{
    __shared__ unsigned short sAH[64 * 64], sAL[64 * 64];     // [row][k], chunk-swizzled
    __shared__ unsigned short sBH[128 * 64], sBL[128 * 64];   // [col][k], chunk-swizzled
    __shared__ float sred[4][64];
    const int tid  = threadIdx.x;
    const int lane = tid & 63;
    const int wave = tid >> 6;
    const int wr = (wave >> 1) * 32;
    const int wc = (wave & 1) * 64;
    const int row0 = blockIdx.x * 64, col0 = blockIdx.y * 128;

    f32x4 acc[2][4];
#pragma unroll
    for (int i = 0; i < 2; i++)
#pragma unroll
        for (int j = 0; j < 4; j++) acc[i][j] = (f32x4){0.f, 0.f, 0.f, 0.f};

    const int a_r  = tid >> 2;
    const int a_cp = (tid & 3) * 2;
    const unsigned short* ApH = AH + (size_t)(row0 + a_r) * K + a_cp * 8;
    const unsigned short* ApL = AL + (size_t)(row0 + a_r) * K + a_cp * 8;
    const int a_sw = a_r & 7;
    const int a_s0 = a_r * 64 + (((a_cp + 0) ^ a_sw) << 3);
    const int a_s1 = a_r * 64 + (((a_cp + 1) ^ a_sw) << 3);

    const int b_c  = tid >> 1;
    const int b_cp = (tid & 1) * 4;
    const unsigned short* BpH = BTH + (size_t)(col0 + b_c) * K + b_cp * 8;
    const unsigned short* BpL = BTL + (size_t)(col0 + b_c) * K + b_cp * 8;
    const int b_sw = b_c & 7;
    int b_s[4];
#pragma unroll
    for (int i = 0; i < 4; i++) b_s[i] = b_c * 64 + (((b_cp + i) ^ b_sw) << 3);

    const int l15 = lane & 15;
    const int kc  = lane >> 4;

    // prologue: load tile 0 into registers
    ushort8 vah0 = *reinterpret_cast<const ushort8*>(ApH);
    ushort8 vah1 = *reinterpret_cast<const ushort8*>(ApH + 8);
    ushort8 val0 = *reinterpret_cast<const ushort8*>(ApL);
    ushort8 val1 = *reinterpret_cast<const ushort8*>(ApL + 8);
    ushort8 vbh[4], vbl[4];
#pragma unroll
    for (int i = 0; i < 4; i++) {
        vbh[i] = *reinterpret_cast<const ushort8*>(BpH + i * 8);
        vbl[i] = *reinterpret_cast<const ushort8*>(BpL + i * 8);
    }

    for (int k0 = 0; k0 < K; k0 += 64) {
        __syncthreads();
        *reinterpret_cast<ushort8*>(&sAH[a_s0]) = vah0;
        *reinterpret_cast<ushort8*>(&sAH[a_s1]) = vah1;
        *reinterpret_cast<ushort8*>(&sAL[a_s0]) = val0;
        *reinterpret_cast<ushort8*>(&sAL[a_s1]) = val1;
#pragma unroll
        for (int i = 0; i < 4; i++) {
            *reinterpret_cast<ushort8*>(&sBH[b_s[i]]) = vbh[i];
            *reinterpret_cast<ushort8*>(&sBL[b_s[i]]) = vbl[i];
        }
        __syncthreads();

        if (k0 + 64 < K) {
            int kn = k0 + 64;
            vah0 = *reinterpret_cast<const ushort8*>(ApH + kn);
            vah1 = *reinterpret_cast<const ushort8*>(ApH + kn + 8);
            val0 = *reinterpret_cast<const ushort8*>(ApL + kn);
            val1 = *reinterpret_cast<const ushort8*>(ApL + kn + 8);
#pragma unroll
            for (int i = 0; i < 4; i++) {
                vbh[i] = *reinterpret_cast<const ushort8*>(BpH + kn + i * 8);
                vbl[i] = *reinterpret_cast<const ushort8*>(BpL + kn + i * 8);
            }
        }

#pragma unroll
        for (int ks = 0; ks < 2; ks++) {
            const int ch = ks * 4 + kc;
            bf16x8 aH[2], aL[2], bH[4], bL[4];
#pragma unroll
            for (int fi = 0; fi < 2; fi++) {
                int r = wr + fi * 16 + l15;
                int sidx = r * 64 + ((ch ^ (r & 7)) << 3);
                aH[fi] = *reinterpret_cast<const bf16x8*>(&sAH[sidx]);
                aL[fi] = *reinterpret_cast<const bf16x8*>(&sAL[sidx]);
            }
#pragma unroll
            for (int fj = 0; fj < 4; fj++) {
                int c = wc + fj * 16 + l15;
                int sidx = c * 64 + ((ch ^ (c & 7)) << 3);
                bH[fj] = *reinterpret_cast<const bf16x8*>(&sBH[sidx]);
                bL[fj] = *reinterpret_cast<const bf16x8*>(&sBL[sidx]);
            }
#pragma unroll
            for (int fi = 0; fi < 2; fi++)
#pragma unroll
                for (int fj = 0; fj < 4; fj++) {
                    acc[fi][fj] = __builtin_amdgcn_mfma_f32_16x16x32_bf16(aH[fi], bH[fj], acc[fi][fj], 0, 0, 0);
                    acc[fi][fj] = __builtin_amdgcn_mfma_f32_16x16x32_bf16(aH[fi], bL[fj], acc[fi][fj], 0, 0, 0);
                    acc[fi][fj] = __builtin_amdgcn_mfma_f32_16x16x32_bf16(aL[fi], bH[fj], acc[fi][fj], 0, 0, 0);
                }
        }
    }

    float pwl[4], asl[4], adl[4];
    if (scv) {
#pragma unroll
        for (int fj = 0; fj < 4; fj++) pwl[fj] = pwv[wc + fj * 16 + l15];
    }
    const int hd = blockIdx.y;
    if (esv) {
#pragma unroll
        for (int fj = 0; fj < 4; fj++) {
            int cl = wc + fj * 16 + l15;
            asl[fj] = asv[hd * 128 + cl];
            adl[fj] = adv[hd * 128 + cl];
        }
    }
    float pd[2][4]  = {{0.f,0.f,0.f,0.f},{0.f,0.f,0.f,0.f}};
    float pds[2][4] = {{0.f,0.f,0.f,0.f},{0.f,0.f,0.f,0.f}};
    float pdd[2][4] = {{0.f,0.f,0.f,0.f},{0.f,0.f,0.f,0.f}};
#pragma unroll
    for (int fi = 0; fi < 2; fi++) {
        int rbase = row0 + wr + fi * 16 + (lane >> 4) * 4;
#pragma unroll
        for (int q = 0; q < 4; q++) {
            int r = rbase + q;
#pragma unroll
            for (int fj = 0; fj < 4; fj++) {
                int c = col0 + wc + fj * 16 + l15;
                float v = acc[fi][fj][q];
                if (bias) v += bias[c];
                if (relu) v = fmaxf(v, 0.f);
                C[(size_t)r * N + c] = v;
                if (scv) pd[fi][q] += v * pwl[fj];
                if (esv) { pds[fi][q] += v * asl[fj]; pdd[fi][q] += v * adl[fj]; }
            }
        }
    }
    if (scv) {
        float rn0 = rnormp[0];
#pragma unroll
        for (int fi = 0; fi < 2; fi++)
#pragma unroll
            for (int q = 0; q < 4; q++) {
                float s = pd[fi][q];
                s += __shfl_xor(s, 1);
                s += __shfl_xor(s, 2);
                s += __shfl_xor(s, 4);
                s += __shfl_xor(s, 8);
                if (l15 == 0) sred[wc >> 6][wr + fi * 16 + (lane >> 4) * 4 + q] = s;
            }
        __syncthreads();
        if (tid < 64)
            scv[row0 + tid] = tanhf((sred[0][tid] + sred[1][tid]) * rn0);
    }
    if (esv) {
#pragma unroll
        for (int fi = 0; fi < 2; fi++)
#pragma unroll
            for (int q = 0; q < 4; q++) {
                float s = pds[fi][q];
                s += __shfl_xor(s, 1);
                s += __shfl_xor(s, 2);
                s += __shfl_xor(s, 4);
                s += __shfl_xor(s, 8);
                float d = pdd[fi][q];
                d += __shfl_xor(d, 1);
                d += __shfl_xor(d, 2);
                d += __shfl_xor(d, 4);
                d += __shfl_xor(d, 8);
                if (l15 == 0) {
                    int rl = wr + fi * 16 + (lane >> 4) * 4 + q;
                    sred[wc >> 6][rl] = s;
                    sred[2 + (wc >> 6)][rl] = d;
                }
            }
        __syncthreads();
        if (tid < 64) {
            int r = row0 + tid;
            esv[(size_t)r * 3 + hd] = sred[0][tid] + sred[1][tid];
            edv[(size_t)r * 3 + hd] = sred[2][tid] + sred[3][tid];
        }
    }
}

// ---------------- small-M GEMM (MLP head, M=64): one thread per output ----------------
__global__ __launch_bounds__(256) void gemm_small_k(const float* __restrict__ A,
                                                    const float* __restrict__ B,
                                                    const float* __restrict__ bias,
                                                    float* __restrict__ C,
                                                    int M, int K, int N, int relu)
{
    int idx = blockIdx.x * 256 + threadIdx.x;
    if (idx >= M * N) return;
    int r = idx / N, c = idx - r * N;
    const float* ap = A + (size_t)r * K;
    const float* bp = B + c;
    float s = 0.f;
#pragma unroll 8
    for (int k = 0; k < K; k++) s += ap[k] * bp[(size_t)k * N];
    if (bias) s += bias[c];
    if (relu) s = fmaxf(s, 0.f);
    C[idx] = s;
}

// ---------------- per-graph CSR build + softmax max/den (one 512-thr block per graph) ----------------
__global__ __launch_bounds__(512) void csr_k(const int* __restrict__ src,
                                             const int* __restrict__ dst,
                                             const int* __restrict__ valid,
                                             const float* __restrict__ es,
                                             const float* __restrict__ ed,
                                             int* __restrict__ csr,
                                             int* __restrict__ beg,
                                             int* __restrict__ end,
                                             float* __restrict__ wmx,
                                             float* __restrict__ winv,
                                             float* __restrict__ wself,
                                             int per)
{
    __shared__ int sdeg[512];
    __shared__ int soff[512];
    __shared__ float ses[1536];
    __shared__ float sed[1536];
    const int g = blockIdx.x;
    const int t = threadIdx.x;
    const int bn = g * per;
    const int be = g * 2048;
    sdeg[t] = 0;
    for (int i = t; i < per * 3; i += 512) {
        ses[i] = es[(size_t)bn * 3 + i];
        sed[i] = ed[(size_t)bn * 3 + i];
    }
    __syncthreads();
#pragma unroll
    for (int j = 0; j < 4; j++) {
        int e = be + j * 512 + t;
        if (!valid || valid[e]) atomicAdd(&sdeg[dst[e] - bn], 1);
    }
    __syncthreads();
    soff[t] = sdeg[t];
    __syncthreads();
    for (int d = 1; d < 512; d <<= 1) {
        int v = (t >= d) ? soff[t - d] : 0;
        __syncthreads();
        soff[t] += v;
        __syncthreads();
    }
    const int deg_t = sdeg[t];
    const int excl = soff[t] - deg_t;
    if (t < per) { beg[bn + t] = be + excl; end[bn + t] = be + excl + deg_t; }
    __syncthreads();
    sdeg[t] = excl;
    __syncthreads();
#pragma unroll
    for (int j = 0; j < 4; j++) {
        int e = be + j * 512 + t;
        if (!valid || valid[e]) {
            int p = atomicAdd(&sdeg[dst[e] - bn], 1);
            csr[be + p] = e;
        }
    }
    __syncthreads();
    if (t < per) {
        float edv[3], m[3], den[3], selfl[3];
#pragma unroll
        for (int h = 0; h < 3; h++) {
            edv[h] = sed[t * 3 + h];
            selfl[h] = lrelu(ses[t * 3 + h] + edv[h]);
            m[h] = selfl[h];
            den[h] = 1.f;
        }
        const int pb = excl, pe = excl + deg_t;
        for (int p = pb; p < pe; p++) {
            int e = csr[be + p];
            int sl = src[e] - bn;
#pragma unroll
            for (int h = 0; h < 3; h++) {
                float l = lrelu(ses[sl * 3 + h] + edv[h]);
                if (l <= m[h]) den[h] += __expf(l - m[h]);
                else { den[h] = den[h] * __expf(m[h] - l) + 1.f; m[h] = l; }
            }
        }
#pragma unroll
        for (int h = 0; h < 3; h++) {
            float inv = 1.f / (den[h] + 1e-16f);
            wmx[(size_t)(bn + t) * 3 + h] = m[h];
            winv[(size_t)(bn + t) * 3 + h] = inv;
            wself[(size_t)(bn + t) * 3 + h] = __expf(selfl[h] - m[h]) * inv;
        }
    }
}

// ---------------- alpha+gather fused: one wave per dst, lane-parallel weight precompute ----------------
__global__ __launch_bounds__(256) void agg2_k(const float* __restrict__ H,
                                              const float* __restrict__ es,
                                              const float* __restrict__ ed,
                                              const float* __restrict__ wmx,
                                              const float* __restrict__ winv,
                                              const float* __restrict__ wself,
                                              const int* __restrict__ beg,
                                              const int* __restrict__ end,
                                              const int* __restrict__ csr,
                                              const int* __restrict__ srcArr,
                                              const float* __restrict__ bias,
                                              unsigned short* __restrict__ outH,
                                              unsigned short* __restrict__ outL, int n)
{
    int nwg = gridDim.x;
    int bid = blockIdx.x;
    int swz = (bid & 7) * (nwg >> 3) + (bid >> 3);
    int wid = swz * 4 + (int)(threadIdx.x >> 6);
    int lane = threadIdx.x & 63;
    if (wid >= n) return;
    const int d = wid;
    float edv[3], mxv[3], ivv[3], wsf[3];
#pragma unroll
    for (int h = 0; h < 3; h++) {
        edv[h] = ed[(size_t)d * 3 + h];
        mxv[h] = wmx[(size_t)d * 3 + h];
        ivv[h] = winv[(size_t)d * 3 + h];
        wsf[h] = wself[(size_t)d * 3 + h];
    }
    float acc[6];
    const float* hp = H + (size_t)d * 384;
#pragma unroll
    for (int j = 0; j < 6; j++) acc[j] = wsf[j >> 1] * hp[lane + 64 * j];
    const int pb = beg[d], pe = end[d];
    for (int base = pb; base < pe; base += 64) {
        const int cnt = min(64, pe - base);
        int sl = 0;
        float wl0 = 0.f, wl1 = 0.f, wl2 = 0.f;
        if (lane < cnt) {
            int e = csr[base + lane];
            int s = srcArr[e];
            sl = s;
            wl0 = __expf(lrelu(es[(size_t)s * 3 + 0] + edv[0]) - mxv[0]) * ivv[0];
            wl1 = __expf(lrelu(es[(size_t)s * 3 + 1] + edv[1]) - mxv[1]) * ivv[1];
            wl2 = __expf(lrelu(es[(size_t)s * 3 + 2] + edv[2]) - mxv[2]) * ivv[2];
        }
        for (int j = 0; j < cnt; j++) {
            int s = __shfl(sl, j);
            float w0 = __shfl(wl0, j);
            float w1 = __shfl(wl1, j);
            float w2 = __shfl(wl2, j);
            const float* sp = H + (size_t)s * 384;
            acc[0] += w0 * sp[lane];
            acc[1] += w0 * sp[lane + 64];
            acc[2] += w1 * sp[lane + 128];
            acc[3] += w1 * sp[lane + 192];
            acc[4] += w2 * sp[lane + 256];
            acc[5] += w2 * sp[lane + 320];
        }
    }
#pragma unroll
    for (int j = 0; j < 6; j++) {
        float v = acc[j] + bias[lane + 64 * j];
        unsigned short h = f2bf(v);
        outH[(size_t)d * 384 + lane + 64 * j] = h;
        outL[(size_t)d * 384 + lane + 64 * j] = f2bf(v - bf2f(h));
    }
}

// ---------------- per-graph top-k select + fused edge remap (u64-packed bitonic) ----------------
__global__ __launch_bounds__(512) void select_k(const float* __restrict__ sc,
                                                const int* __restrict__ s_old,
                                                const int* __restrict__ d_old,
                                                const int* __restrict__ v_old,
                                                int per, int k,
                                                int* __restrict__ perm, float* __restrict__ ps,
                                                int* __restrict__ s_new,
                                                int* __restrict__ d_new,
                                                int* __restrict__ v_new)
{
    __shared__ unsigned long long skey[512];
    __shared__ int snew[512];
    const int b = blockIdx.x;
    const int t = threadIdx.x;
    const int bn = b * per;

    if (t < per) {
        unsigned o = ~ordmap(sc[bn + t]);
        skey[t] = ((unsigned long long)o << 32) | (unsigned)t;
    } else {
        skey[t] = 0xFFFFFFFFFFFFFFFFull;
    }
    __syncthreads();
    for (int kk = 2; kk <= 512; kk <<= 1)
        for (int j = kk >> 1; j > 0; j >>= 1) {
            int ixj = t ^ j;
            if (ixj > t) {
                unsigned long long a = skey[t], bq = skey[ixj];
                bool up = ((t & kk) == 0);
                if (up ? (a > bq) : (a < bq)) { skey[t] = bq; skey[ixj] = a; }
            }
            __syncthreads();
        }
    {
        unsigned long long kv = skey[t];
        int idx = (int)(kv & 0xFFFFFFFFull);
        if (idx < per) snew[idx] = (t < k) ? (b * k + t) : -1;
        if (t < k) {
            perm[b * k + t] = bn + idx;
            ps[b * k + t] = ordinv(~(unsigned)(kv >> 32));
        }
    }
    __syncthreads();

    if (s_new) {
        const int be = b * 2048;
#pragma unroll
        for (int j = 0; j < 4; j++) {
            int e = be + j * 512 + t;
            int v = v_old ? v_old[e] : 1;
            int ns = -1, nd = -1;
            if (v) { ns = snew[s_old[e] - bn]; nd = snew[d_old[e] - bn]; }
            int ok = (v && ns >= 0 && nd >= 0) ? 1 : 0;
            s_new[e] = ok ? ns : 0;
            d_new[e] = ok ? nd : 0;
            v_new[e] = ok;
        }
    }
}

// ---------------- gated copy of kept nodes: bf16 hi/lo only (one wave per new node) ----------------
__global__ __launch_bounds__(256) void gate_k(const float* __restrict__ H,
                                              const int* __restrict__ perm,
                                              const float* __restrict__ ps,
                                              unsigned short* __restrict__ XH,
                                              unsigned short* __restrict__ XL, int nNew)
{
    int wid = (int)((blockIdx.x * 256 + threadIdx.x) >> 6);
    int lane = threadIdx.x & 63;
    if (wid >= nNew) return;
    int o = perm[wid];
    float g = ps[wid];
    float v0 = H[(size_t)o * 128 + lane] * g;
    float v1 = H[(size_t)o * 128 + 64 + lane] * g;
    unsigned short h0 = f2bf(v0), h1 = f2bf(v1);
    XH[(size_t)wid * 128 + lane] = h0;
    XH[(size_t)wid * 128 + 64 + lane] = h1;
    XL[(size_t)wid * 128 + lane] = f2bf(v0 - bf2f(h0));
    XL[(size_t)wid * 128 + 64 + lane] = f2bf(v1 - bf2f(h1));
}

// ---------------- combined global max+mean pool over all three layers (bf16 hi/lo inputs) ----------------
__global__ __launch_bounds__(1024) void gpool3_k(const unsigned short* __restrict__ X1H,
                                                 const unsigned short* __restrict__ X1L,
                                                 const unsigned short* __restrict__ X2H,
                                                 const unsigned short* __restrict__ X2L,
                                                 const unsigned short* __restrict__ X3H,
                                                 const unsigned short* __restrict__ X3L,
                                                 int k1, int k2, int k3,
                                                 float* __restrict__ z)
{
    __shared__ float smx[8][128];
    __shared__ float ssm[8][128];
    const int b = blockIdx.x;
    const int col = threadIdx.x & 127;
    const int rg = threadIdx.x >> 7;
    const unsigned short* XsH[3] = {X1H, X2H, X3H};
    const unsigned short* XsL[3] = {X1L, X2L, X3L};
    const int ks[3] = {k1, k2, k3};
    float accm = 0.f, accs = 0.f;
#pragma unroll
    for (int L = 0; L < 3; L++) {
        const int k = ks[L];
        const unsigned short* xh = XsH[L] + (size_t)b * k * 128 + col;
        const unsigned short* xl = XsL[L] + (size_t)b * k * 128 + col;
        float mx = -FLT_MAX, sm = 0.f;
        int r = rg;
#pragma unroll 4
        for (; r + 32 <= k; r += 32) {
            float v0 = bf2f(xh[(size_t)(r + 0)  * 128]) + bf2f(xl[(size_t)(r + 0)  * 128]);
            float v1 = bf2f(xh[(size_t)(r + 8)  * 128]) + bf2f(xl[(size_t)(r + 8)  * 128]);
            float v2 = bf2f(xh[(size_t)(r + 16) * 128]) + bf2f(xl[(size_t)(r + 16) * 128]);
            float v3 = bf2f(xh[(size_t)(r + 24) * 128]) + bf2f(xl[(size_t)(r + 24) * 128]);
            mx = fmaxf(fmaxf(fmaxf(mx, v0), fmaxf(v1, v2)), v3);
            sm += v0 + v1 + v2 + v3;
        }
        for (; r < k; r += 8) {
            float v = bf2f(xh[(size_t)r * 128]) + bf2f(xl[(size_t)r * 128]);
            mx = fmaxf(mx, v);
            sm += v;
        }
        smx[rg][col] = mx;
        ssm[rg][col] = sm;
        __syncthreads();
        if (rg == 0) {
#pragma unroll
            for (int i = 1; i < 8; i++) { mx = fmaxf(mx, smx[i][col]); sm += ssm[i][col]; }
            accm += mx;
            accs += sm / (float)k;
        }
        __syncthreads();
    }
    if (rg == 0) {
        z[b * 256 + col] = accm;
        z[b * 256 + 128 + col] = accs;
    }
}

extern "C" void kernel_launch(void* const* d_in, const int* in_sizes, int n_in,
                              void* d_out, int out_size, void* d_ws, size_t ws_size,
                              hipStream_t stream)
{
    (void)in_sizes; (void)n_in; (void)out_size; (void)ws_size;

    const float* x   = (const float*)d_in[0];
    const int*   ei  = (const int*)d_in[2];
    const float* W1  = (const float*)d_in[4];
    const float* as1 = (const float*)d_in[5];
    const float* ad1 = (const float*)d_in[6];
    const float* b1  = (const float*)d_in[7];
    const float* Wh1 = (const float*)d_in[8];
    const float* bh1 = (const float*)d_in[9];
    const float* pw1 = (const float*)d_in[10];
    const float* W2  = (const float*)d_in[11];
    const float* as2 = (const float*)d_in[12];
    const float* ad2 = (const float*)d_in[13];
    const float* b2  = (const float*)d_in[14];
    const float* Wh2 = (const float*)d_in[15];
    const float* bh2 = (const float*)d_in[16];
    const float* pw2 = (const float*)d_in[17];
    const float* W3  = (const float*)d_in[18];
    const float* as3 = (const float*)d_in[19];
    const float* ad3 = (const float*)d_in[20];
    const float* b3  = (const float*)d_in[21];
    const float* Wh3 = (const float*)d_in[22];
    const float* bh3 = (const float*)d_in[23];
    const float* pw3 = (const float*)d_in[24];
    const float* Wl1 = (const float*)d_in[25];
    const float* bl1 = (const float*)d_in[26];
    const float* Wl2 = (const float*)d_in[27];
    const float* bl2 = (const float*)d_in[28];
    float* out = (float*)d_out;

    const int E = 131072;
    const int n1 = 32768, per1 = 512, k1 = 410;
    const int n2 = 64 * k1, per2 = k1, k2 = 205;   // 26240, 410, 205
    const int n3 = 64 * k2, per3 = k2, k3 = 41;    // 13120, 205, 41
    const int n4 = 64 * k3;                        // 2624

    // ---- workspace carve ----
    char* wsb = (char*)d_ws;
    size_t off = 0;
    auto alloc = [&](size_t bytes) -> void* {
        void* p = wsb + off;
        off += (bytes + 255) & ~(size_t)255;
        return p;
    };
    float* A    = (float*)alloc((size_t)n1 * 384 * 4);
    unsigned short* BfH = (unsigned short*)alloc((size_t)n1 * 384 * 2);
    unsigned short* BfL = (unsigned short*)alloc((size_t)n1 * 384 * 2);
    unsigned short* X0H = (unsigned short*)alloc((size_t)n1 * 128 * 2);
    unsigned short* X0L = (unsigned short*)alloc((size_t)n1 * 128 * 2);
    unsigned short* X1H = (unsigned short*)alloc((size_t)n2 * 128 * 2);
    unsigned short* X1L = (unsigned short*)alloc((size_t)n2 * 128 * 2);
    unsigned short* X2H = (unsigned short*)alloc((size_t)n3 * 128 * 2);
    unsigned short* X2L = (unsigned short*)alloc((size_t)n3 * 128 * 2);
    unsigned short* X3H = (unsigned short*)alloc((size_t)n4 * 128 * 2);
    unsigned short* X3L = (unsigned short*)alloc((size_t)n4 * 128 * 2);
    unsigned short* WT[6], *WTl[6];
    for (int i = 0; i < 6; i++) {
        WT[i]  = (unsigned short*)alloc((size_t)49152 * 2);
        WTl[i] = (unsigned short*)alloc((size_t)49152 * 2);
    }
    float* ES   = (float*)alloc((size_t)n1 * 3 * 4);
    float* ED   = (float*)alloc((size_t)n1 * 3 * 4);
    float* SC   = (float*)alloc((size_t)n1 * 4);
    int*   CSR  = (int*)alloc((size_t)E * 4);
    int*   BEG  = (int*)alloc((size_t)n1 * 4);
    int*   END  = (int*)alloc((size_t)n1 * 4);
    int*   SRCA = (int*)alloc((size_t)E * 4);
    int*   DSTA = (int*)alloc((size_t)E * 4);
    int*   VALA = (int*)alloc((size_t)E * 4);
    int*   SRCB = (int*)alloc((size_t)E * 4);
    int*   DSTB = (int*)alloc((size_t)E * 4);
    int*   VALB = (int*)alloc((size_t)E * 4);
    int*   PERM = (int*)alloc((size_t)n2 * 4);
    float* PSC  = (float*)alloc((size_t)n2 * 4);
    float* WMX  = (float*)alloc((size_t)n1 * 3 * 4);
    float* WINV = (float*)alloc((size_t)n1 * 3 * 4);
    float* WSELF= (float*)alloc((size_t)n1 * 3 * 4);
    float* RN   = (float*)alloc((size_t)4 * 4);
    float* Z    = (float*)alloc((size_t)64 * 256 * 4);
    float* ZH   = (float*)alloc((size_t)64 * 512 * 4);

    // ---- upfront: operand split + 1/||pw|| (fused) ----
    {
        Segs S;
        const float* srcs[7] = {x, W1, Wh1, W2, Wh2, W3, Wh3};
        unsigned short* dh[7] = {X0H, WT[0], WT[1], WT[2], WT[3], WT[4], WT[5]};
        unsigned short* dl[7] = {X0L, WTl[0], WTl[1], WTl[2], WTl[3], WTl[4], WTl[5]};
        int rows[7] = {n1, 128, 384, 128, 384, 128, 384};
        int cols[7] = {128, 384, 128, 384, 128, 384, 128};
        int trs[7]  = {0, 1, 1, 1, 1, 1, 1};
        int cum = 0;
        for (int i = 0; i < 7; i++) {
            S.seg[i] = SegT{srcs[i], dh[i], dl[i], rows[i], cols[i], trs[i]};
            S.cum[i] = cum;
            cum += rows[i] * cols[i];
        }
        S.cum[7] = cum;
        split_k<<<(cum + 255) / 256 + 1, 256, 0, stream>>>(S, cum, pw1, pw2, pw3, RN);
    }

    auto layer = [&](const unsigned short* xh, const unsigned short* xl,
                     int n, int per, int kk, int lidx,
                     const int* src, const int* dst, const int* val,
                     const unsigned short* wt, const unsigned short* wtl,
                     const float* as_, const float* ad_, const float* bb,
                     const unsigned short* wht, const unsigned short* whtl, const float* bh,
                     const float* pw,
                     unsigned short* XnH, unsigned short* XnL,
                     int* srcN, int* dstN, int* valN)
    {
        int nNew = 64 * kk;
        // GEMM-1 with fused e_src/e_dst epilogue (blockIdx.y == head)
        gemm_bf2_k<<<dim3(n / 64, 3), 256, 0, stream>>>(xh, xl, wt, wtl, nullptr, A, n, 128, 384, 0,
                                                        nullptr, nullptr, nullptr,
                                                        as_, ad_, ES, ED);
        csr_k<<<64, 512, 0, stream>>>(src, dst, val, ES, ED, CSR, BEG, END, WMX, WINV, WSELF, per);
        agg2_k<<<n / 4, 256, 0, stream>>>(A, ES, ED, WMX, WINV, WSELF, BEG, END, CSR, src, bb, BfH, BfL, n);
        // GEMM-2 with fused score epilogue
        gemm_bf2_k<<<dim3(n / 64, 1), 256, 0, stream>>>(BfH, BfL, wht, whtl, bh, A, n, 384, 128, 1,
                                                        pw, RN + lidx, SC,
                                                        nullptr, nullptr, nullptr, nullptr);
        select_k<<<64, 512, 0, stream>>>(SC, src, dst, val, per, kk, PERM, PSC, srcN, dstN, valN);
        gate_k<<<nNew / 4, 256, 0, stream>>>(A, PERM, PSC, XnH, XnL, nNew);
    };

    layer(X0H, X0L, n1, per1, k1, 0, ei,   ei + E, nullptr,
          WT[0], WTl[0], as1, ad1, b1, WT[1], WTl[1], bh1, pw1,
          X1H, X1L, SRCA, DSTA, VALA);
    layer(X1H, X1L, n2, per2, k2, 1, SRCA, DSTA, VALA,
          WT[2], WTl[2], as2, ad2, b2, WT[3], WTl[3], bh2, pw2,
          X2H, X2L, SRCB, DSTB, VALB);
    layer(X2H, X2L, n3, per3, k3, 2, SRCB, DSTB, VALB,
          WT[4], WTl[4], as3, ad3, b3, WT[5], WTl[5], bh3, pw3,
          X3H, X3L, nullptr, nullptr, nullptr);

    gpool3_k<<<64, 1024, 0, stream>>>(X1H, X1L, X2H, X2L, X3H, X3L, k1, k2, k3, Z);

    gemm_small_k<<<(64 * 512 + 255) / 256, 256, 0, stream>>>(Z,  Wl1, bl1, ZH,  64, 256, 512, 1);
    gemm_small_k<<<(64 * 256 + 255) / 256, 256, 0, stream>>>(ZH, Wl2, bl2, out, 64, 512, 256, 0);
}